// Round 10
// baseline (100.800 us; speedup 1.0000x reference)
//
#include <hip/hip_runtime.h>

#define D 256
#define NB 8192
#define NKC 128            // 8-elem k-chunks per 64-o panel (K=1024 packed)
#define PANEL (NKC * 512)  // 65536 bf16 elems per panel

#define ACH 260            // A-LDS chunk stride in elems (32 rows x 8 k = 256, +4 pad)
#define A_ELEMS (128 * ACH)                     // 33280 elems = 66560 B
#define SMEM_BYTES ((A_ELEMS + 8 * 4096) * 2)   // + 8 waves x 8KB staging = 132096 B

typedef __bf16 bf16;
typedef bf16 bf16x8 __attribute__((ext_vector_type(8)));
typedef bf16 bf16x4 __attribute__((ext_vector_type(4)));
typedef float f32x4 __attribute__((ext_vector_type(4)));

// global_load_lds: GLOBAL address is PER-LANE; LDS dest = wave-uniform base,
// lane i lands at base + i*16B.
__device__ __forceinline__ void glds16(const bf16* g, bf16* l) {
    __builtin_amdgcn_global_load_lds((const __attribute__((address_space(1))) void*)g,
                                     (__attribute__((address_space(3))) void*)l, 16, 0, 0);
}

__device__ __forceinline__ float fast_tanh(float x) {
    float e = __expf(2.f * x);
    return 1.f - 2.f / (e + 1.f);
}

// ---------------------------------------------------------------------------
// pack: coefs[l][i][o][c] fp32 -> tiled W planes c in order [1,4,2,3]
// (element (o, k'=plane*256+i) at panel + (k'>>3)*512 + (o&63)*8 + (k'&7));
// blocks 128..135: beta[l][o] = sum_i coefs[l][i][o][0].  [r8-verified]
// ---------------------------------------------------------------------------
__global__ __launch_bounds__(256) void pack_kernel(const float* __restrict__ coefs,
                                                   bf16* __restrict__ Wt,
                                                   float* __restrict__ beta) {
    __shared__ float t[64 * 65];
    __shared__ float accs[4][64];
    int b = blockIdx.x;
    if (b < 128) {
        int l = b >> 6, rem = b & 63;
        int c = (rem >> 4) + 1, tl = rem & 15;
        int plane = (c == 1) ? 0 : (c == 4) ? 1 : (c == 2) ? 2 : 3;
        int i0 = (tl >> 2) * 64, o0 = (tl & 3) * 64;

        for (int j = threadIdx.x; j < 4096; j += 256) {
            int i = j >> 6, o = j & 63;
            t[i * 65 + o] = coefs[(((size_t)(l * 256 + i0 + i)) * 256 + (o0 + o)) * 5 + c];
        }
        __syncthreads();
        bf16* dst = Wt + (size_t)l * (4 * PANEL)
                       + ((size_t)(tl & 3) * NKC + (plane * 256 + i0) / 8) * 512;
        for (int j = threadIdx.x; j < 4096; j += 256) {
            int il = j & 7, o = (j >> 3) & 63, ih = j >> 9;
            dst[j] = (bf16)t[(ih * 8 + il) * 65 + o];
        }
    } else {
        int lidx = b - 128;
        int l = lidx >> 2, o0 = (lidx & 3) * 64;
        int o = threadIdx.x & 63, ig = threadIdx.x >> 6;
        float sum = 0.f;
        for (int m = 0; m < 64; ++m) {
            int i = ig * 64 + m;
            sum += coefs[(((size_t)(l * 256 + i)) * 256 + (o0 + o)) * 5 + 0];
        }
        accs[ig][o] = sum;
        __syncthreads();
        if (threadIdx.x < 64)
            beta[l * 256 + o0 + threadIdx.x] = accs[0][threadIdx.x] + accs[1][threadIdx.x]
                                             + accs[2][threadIdx.x] + accs[3][threadIdx.x];
    }
}

// ---------------------------------------------------------------------------
// Fused 2-layer kernel. Block = 32-row slab x all 256 cols, 8 waves =
// 4 col-panels (g) x 2 k-halves (p). Per layer:
//  LN+Jacobi: each wave computes P1..P4 ONCE per element (fp32 x) and writes
//    all plane fragments into A-LDS (chunk cc = slot*32 + i>>3, slot order
//    [P1,P4,P2,P3] matching the packed W plane order; stride 520B -> 2-way
//    banks). Kills the 4x col-group Jacobi duplication of r9.
//  K-loop: uniform 16 iters BK=32; A and W frags both via ds_read_b128;
//    W glds16 dbuf, steady vmcnt(4), lgkm0+sched_barrier WAR fence.
//  Race fix vs r9: prologue glds AFTER the post-LN barrier (h1 panels in
//    staging are cross-wave-read by LN; overwriting must wait).
// ---------------------------------------------------------------------------
__global__ __launch_bounds__(512, 2) void fused2_kernel(
    const float* __restrict__ x, const float* __restrict__ ln_scale,
    const float* __restrict__ ln_bias, const float* __restrict__ alphas,
    const bf16* __restrict__ Wt, const float* __restrict__ beta,
    float* __restrict__ out) {
    extern __shared__ __align__(16) bf16 smem[];
    bf16* aL   = smem;                 // A-LDS: 128 chunks x 520 B = 66560 B
    bf16* stag = smem + A_ELEMS;       // 65536 B: wave w owns [w*4096, +4096)

    const int tid = threadIdx.x;
    const int l   = tid & 63;
    const int w   = tid >> 6;
    const int g   = w >> 1, p = w & 1;
    const int slab = blockIdx.x;

    bf16* sW = stag + w * 4096;        // 8 KB dbuf (2 x 4 KB)

#pragma unroll
    for (int L = 0; L < 2; ++L) {
        const float* scale = ln_scale + L * D;
        const float* biasp = ln_bias + L * D;
        const bf16*  Wl    = Wt + (size_t)L * 4 * PANEL;
        const float* bet   = beta + L * D;

        const float a  = tanhf(alphas[L]);
        const float a1 = a + 1.f;
        float rB[3], rC[3];
#pragma unroll
        for (int k = 2; k < 5; k++) {
            float tk  = 2.f * k + 2.f * a;
            float iAk = 1.f / (2.f * k * (k + 2.f * a) * (tk - 2.f));
            rB[k - 2] = (tk - 1.f) * tk * (tk - 2.f) * iAk;
            rC[k - 2] = 2.f * (k + a - 1.f) * (k + a - 1.f) * tk * iAk;
        }

        float4 sc4 = ((const float4*)scale)[l];
        float4 bi4 = ((const float4*)biasp)[l];
        float scv[4] = {sc4.x, sc4.y, sc4.z, sc4.w};
        float biv[4] = {bi4.x, bi4.y, bi4.z, bi4.w};

        // --- LN + Jacobi -> A-LDS: wave w owns rows 4w..4w+3, lane i=4l..4l+3 ---
#pragma unroll
        for (int rr = 0; rr < 4; ++rr) {
            int lr = w * 4 + rr;
            float4 v;
            if (L == 0) {
                v = ((const float4*)(x + ((size_t)slab * 32 + lr) * D))[l];
            } else {
                const float* hp = (const float*)(stag + (size_t)(l >> 4) * 8192);
                v = *(const float4*)(hp + lr * 64 + (l & 15) * 4);
            }
            float s  = v.x + v.y + v.z + v.w;
            float ss = v.x * v.x + v.y * v.y + v.z * v.z + v.w * v.w;
#pragma unroll
            for (int off = 32; off > 0; off >>= 1) {
                s  += __shfl_down(s, off);
                ss += __shfl_down(ss, off);
            }
            s  = __shfl(s, 0);
            ss = __shfl(ss, 0);
            float mu   = s * (1.f / D);
            float rstd = rsqrtf(ss * (1.f / D) - mu * mu + 1e-6f);
            float hv[4] = {v.x, v.y, v.z, v.w};

            bf16x4 o1, o2, o3, o4;
#pragma unroll
            for (int e = 0; e < 4; ++e) {
                float xx = fast_tanh((hv[e] - mu) * rstd * scv[e] + biv[e]);
                float P1 = a1 * xx;
                float P2 = rB[0] * xx * P1 - rC[0];
                float P3 = rB[1] * xx * P2 - rC[1] * P1;
                float P4 = rB[2] * xx * P3 - rC[2] * P2;
                o1[e] = (bf16)P1; o2[e] = (bf16)P2;
                o3[e] = (bf16)P3; o4[e] = (bf16)P4;
            }
            // slot order [P1,P4,P2,P3]; cc = slot*32 + (l>>1)
            size_t base = (size_t)(l >> 1) * ACH + lr * 8 + 4 * (l & 1);
            *(bf16x4*)(aL + base + (size_t)(0 * 32) * ACH) = o1;
            *(bf16x4*)(aL + base + (size_t)(1 * 32) * ACH) = o4;
            *(bf16x4*)(aL + base + (size_t)(2 * 32) * ACH) = o2;
            *(bf16x4*)(aL + base + (size_t)(3 * 32) * ACH) = o3;
        }
        __syncthreads();   // A ready; h1 (L=1) fully consumed -> staging reusable

        // --- prologue W prefetch (after barrier: no WAR on h1 panels) ---
        const bf16* Wp = Wl + (size_t)g * PANEL;
#pragma unroll
        for (int itp = 0; itp < 2; ++itp) {
            bf16* dst = sW + itp * 2048;
            const int chunk = p * 16 + itp;     // 2048-elem iter-blocks, sequential
#pragma unroll
            for (int t = 0; t < 4; ++t)
                glds16(Wp + chunk * 2048 + t * 512 + l * 8, dst + t * 512);
        }

        f32x4 acc[2][4] = {};
#pragma unroll
        for (int it = 0; it < 16; ++it) {
            if (it == 15) __builtin_amdgcn_s_waitcnt(0x0F70);   // vmcnt(0)
            else          __builtin_amdgcn_s_waitcnt(0x0F74);   // vmcnt(4)
            const bf16* sWb = sW + (it & 1) * 2048;

            bf16x8 bfr[4];
#pragma unroll
            for (int tn = 0; tn < 4; ++tn)
                bfr[tn] = *(const bf16x8*)(sWb + (l >> 4) * 512 + (16 * tn + (l & 15)) * 8);

            bf16x8 af[2];
            {
                const int cc = (p * 16 + it) * 4 + (l >> 4);
#pragma unroll
                for (int tm = 0; tm < 2; ++tm)
                    af[tm] = *(const bf16x8*)(aL + (size_t)cc * ACH + (16 * tm + (l & 15)) * 8);
            }

#pragma unroll
            for (int tm = 0; tm < 2; ++tm)
#pragma unroll
                for (int tn = 0; tn < 4; ++tn)
                    acc[tm][tn] = __builtin_amdgcn_mfma_f32_16x16x32_bf16(
                        af[tm], bfr[tn], acc[tm][tn], 0, 0, 0);

            if (it < 14) {
                __builtin_amdgcn_s_waitcnt(0xC07F);        // lgkmcnt(0): WAR fence
                __builtin_amdgcn_sched_barrier(0);
                const int chunk = p * 16 + it + 2;
                bf16* dst = sW + (it & 1) * 2048;
#pragma unroll
                for (int t = 0; t < 4; ++t)
                    glds16(Wp + chunk * 2048 + t * 512 + l * 8, dst + t * 512);
            }
        }

        // --- split-K reduce: p=1 dumps into OWN (idle) staging region ---
        if (p == 1) {
            f32x4* dumpr = (f32x4*)(stag + (size_t)w * 4096);
#pragma unroll
            for (int tm = 0; tm < 2; ++tm)
#pragma unroll
                for (int tn = 0; tn < 4; ++tn)
                    dumpr[(tm * 4 + tn) * 64 + l] = acc[tm][tn];
        }
        __syncthreads();

        if (p == 0) {
            f32x4* part = (f32x4*)(stag + (size_t)(w + 1) * 4096);
            if (L == 0) {
                float* hp = (float*)(stag + (size_t)w * 4096);   // h1 panel g, 32x64 fp32
#pragma unroll
                for (int tm = 0; tm < 2; ++tm)
#pragma unroll
                    for (int tn = 0; tn < 4; ++tn) {
                        int lc = 16 * tn + (l & 15);
                        float bv = bet[g * 64 + lc] * (1.f / 256.f);
                        f32x4 v = acc[tm][tn] + part[(tm * 4 + tn) * 64 + l];
                        int lr0 = 16 * tm + (l >> 4) * 4;        // C/D: row=(l>>4)*4+r
#pragma unroll
                        for (int r = 0; r < 4; ++r)
                            hp[(lr0 + r) * 64 + lc] = v[r] * (1.f / 256.f) + bv;
                    }
            } else {
#pragma unroll
                for (int tm = 0; tm < 2; ++tm)
#pragma unroll
                    for (int tn = 0; tn < 4; ++tn) {
                        int gc = g * 64 + 16 * tn + (l & 15);
                        float bv = bet[gc] * (1.f / 256.f);
                        f32x4 v = acc[tm][tn] + part[(tm * 4 + tn) * 64 + l];
                        int gr = slab * 32 + 16 * tm + (l >> 4) * 4;
#pragma unroll
                        for (int r = 0; r < 4; ++r)
                            out[(size_t)(gr + r) * D + gc] = v[r] * (1.f / 256.f) + bv;
                    }
            }
        }
        __syncthreads();   // h1 visible before next layer's LN
    }
}

// ---------------------------------------------------------------------------
extern "C" void kernel_launch(void* const* d_in, const int* in_sizes, int n_in,
                              void* d_out, int out_size, void* d_ws, size_t ws_size,
                              hipStream_t stream) {
    const float* x        = (const float*)d_in[0];
    const float* coefs    = (const float*)d_in[1];
    const float* alphas   = (const float*)d_in[2];
    const float* ln_scale = (const float*)d_in[3];
    const float* ln_bias  = (const float*)d_in[4];
    float* out = (float*)d_out;

    char* ws = (char*)d_ws;
    bf16*  Wt   = (bf16*)ws;               // 1,048,576 B
    float* beta = (float*)(ws + 1048576);  // 2,048 B

    hipFuncSetAttribute((const void*)fused2_kernel,
                        hipFuncAttributeMaxDynamicSharedMemorySize, SMEM_BYTES);

    pack_kernel<<<136, 256, 0, stream>>>(coefs, Wt, beta);
    fused2_kernel<<<256, 512, SMEM_BYTES, stream>>>(x, ln_scale, ln_bias, alphas,
                                                    Wt, beta, out);
}

// Round 11
// 95.324 us; speedup vs baseline: 1.0574x; 1.0574x over previous
//
#include <hip/hip_runtime.h>

#define D 256
#define NB 8192
#define NKC 128            // 8-elem k-chunks per 64-o panel (K=1024 packed)
#define PANEL (NKC * 512)  // 65536 bf16 elems per panel

#define SXX_STRIDE 264     // 256 + 8 pad -> staggered banks
#define SXX_ELEMS (32 * SXX_STRIDE)               // 8448 elems = 16896 B
#define WREG 8192          // staging region per wave, elems (16 KB: 4 x 4 KB bufs)
#define SMEM_BYTES (SXX_ELEMS * 2 + 8 * WREG * 2) // 16896 + 131072 = 147968 B

typedef __bf16 bf16;
typedef bf16 bf16x8 __attribute__((ext_vector_type(8)));
typedef bf16 bf16x4 __attribute__((ext_vector_type(4)));
typedef float f32x4 __attribute__((ext_vector_type(4)));

// global_load_lds: GLOBAL address is PER-LANE; LDS dest = wave-uniform base,
// lane i lands at base + i*16B.
__device__ __forceinline__ void glds16(const bf16* g, bf16* l) {
    __builtin_amdgcn_global_load_lds((const __attribute__((address_space(1))) void*)g,
                                     (__attribute__((address_space(3))) void*)l, 16, 0, 0);
}

__device__ __forceinline__ float fast_tanh(float x) {
    float e = __expf(2.f * x);
    return 1.f - 2.f / (e + 1.f);
}

// ---------------------------------------------------------------------------
// pack: coefs[l][i][o][c] fp32 -> tiled W planes c in order [1,4,2,3]
// (element (o, k'=plane*256+i) at panel + (k'>>3)*512 + (o&63)*8 + (k'&7));
// blocks 128..135: beta[l][o] = sum_i coefs[l][i][o][0].  [r8-verified]
// ---------------------------------------------------------------------------
__global__ __launch_bounds__(256) void pack_kernel(const float* __restrict__ coefs,
                                                   bf16* __restrict__ Wt,
                                                   float* __restrict__ beta) {
    __shared__ float t[64 * 65];
    __shared__ float accs[4][64];
    int b = blockIdx.x;
    if (b < 128) {
        int l = b >> 6, rem = b & 63;
        int c = (rem >> 4) + 1, tl = rem & 15;
        int plane = (c == 1) ? 0 : (c == 4) ? 1 : (c == 2) ? 2 : 3;
        int i0 = (tl >> 2) * 64, o0 = (tl & 3) * 64;

        for (int j = threadIdx.x; j < 4096; j += 256) {
            int i = j >> 6, o = j & 63;
            t[i * 65 + o] = coefs[(((size_t)(l * 256 + i0 + i)) * 256 + (o0 + o)) * 5 + c];
        }
        __syncthreads();
        bf16* dst = Wt + (size_t)l * (4 * PANEL)
                       + ((size_t)(tl & 3) * NKC + (plane * 256 + i0) / 8) * 512;
        for (int j = threadIdx.x; j < 4096; j += 256) {
            int il = j & 7, o = (j >> 3) & 63, ih = j >> 9;
            dst[j] = (bf16)t[(ih * 8 + il) * 65 + o];
        }
    } else {
        int lidx = b - 128;
        int l = lidx >> 2, o0 = (lidx & 3) * 64;
        int o = threadIdx.x & 63, ig = threadIdx.x >> 6;
        float sum = 0.f;
        for (int m = 0; m < 64; ++m) {
            int i = ig * 64 + m;
            sum += coefs[(((size_t)(l * 256 + i)) * 256 + (o0 + o)) * 5 + 0];
        }
        accs[ig][o] = sum;
        __syncthreads();
        if (threadIdx.x < 64)
            beta[l * 256 + o0 + threadIdx.x] = accs[0][threadIdx.x] + accs[1][threadIdx.x]
                                             + accs[2][threadIdx.x] + accs[3][threadIdx.x];
    }
}

// ---------------------------------------------------------------------------
// K-loop half (r9 pairing + quad-buffer pipeline). Wave p owns planes
// {p*2,p*2+1} = c {1,4} / {2,3}; pair (2j,2j+1) shares i-chunk: one P1->P4
// chain on even iters yields both fragments.  W: 4-deep wave-private dbuf,
// prefetch distance 3, steady-state vmcnt(8) (~3.5 iters latency tolerance),
// WAR fence relaxed to lgkmcnt(4): overwritten buffer was last read a full
// iteration ago, so <=4 remaining (this-iter) lgkm ops proves prior drained.
// ---------------------------------------------------------------------------
template <int PH>
__device__ __forceinline__ void gemm_half(f32x4 (&acc)[2][4], const bf16* __restrict__ Wp,
                                          const bf16* sxx, bf16* sW, int l, float a1,
                                          float rB0, float rB1, float rB2,
                                          float rC0, float rC1, float rC2) {
    bf16x8 afn[2];
#pragma unroll
    for (int it = 0; it < 16; ++it) {
        if (it <= 13)      __builtin_amdgcn_s_waitcnt(0x0F78);   // vmcnt(8)
        else if (it == 14) __builtin_amdgcn_s_waitcnt(0x0F74);   // vmcnt(4)
        else               __builtin_amdgcn_s_waitcnt(0x0F70);   // vmcnt(0)
        const bf16* sWb = sW + (it & 3) * 2048;

        bf16x8 bfr[4];
#pragma unroll
        for (int tn = 0; tn < 4; ++tn)
            bfr[tn] = *(const bf16x8*)(sWb + (l >> 4) * 512 + (16 * tn + (l & 15)) * 8);

        bf16x8 af[2];
        if ((it & 1) == 0) {
            const int j  = it >> 1;
            const int i0 = j * 32 + (l >> 4) * 8;
#pragma unroll
            for (int tm = 0; tm < 2; ++tm) {
                bf16x8 xv = *(const bf16x8*)(sxx + (16 * tm + (l & 15)) * SXX_STRIDE + i0);
#pragma unroll
                for (int jj = 0; jj < 8; ++jj) {
                    float x  = (float)xv[jj];
                    float P1 = a1 * x;
                    float P2 = rB0 * x * P1 - rC0;
                    float P3 = rB1 * x * P2 - rC1 * P1;
                    float PA, PB;
                    if (PH == 0) { PA = P1; PB = rB2 * x * P3 - rC2 * P2; }  // c=1,4
                    else         { PA = P2; PB = P3; }                        // c=2,3
                    af[tm][jj]  = (bf16)PA;
                    afn[tm][jj] = (bf16)PB;
                }
            }
        } else {
            af[0] = afn[0];
            af[1] = afn[1];
        }

#pragma unroll
        for (int tm = 0; tm < 2; ++tm)
#pragma unroll
            for (int tn = 0; tn < 4; ++tn)
                acc[tm][tn] = __builtin_amdgcn_mfma_f32_16x16x32_bf16(
                    af[tm], bfr[tn], acc[tm][tn], 0, 0, 0);

        if (it < 13) {
            __builtin_amdgcn_s_waitcnt(0xC47F);        // lgkmcnt(4): relaxed WAR fence
            __builtin_amdgcn_sched_barrier(0);
            const int sidx  = it + 3;
            const int chunk = (PH * 2 + (sidx & 1)) * 8 + (sidx >> 1);
            bf16* dst = sW + (sidx & 3) * 2048;
#pragma unroll
            for (int t = 0; t < 4; ++t)
                glds16(Wp + chunk * 2048 + t * 512 + l * 8, dst + t * 512);
        }
    }
}

// ---------------------------------------------------------------------------
// Fused 2-layer kernel (r9 structure, r10 race fix, quad-buffer staging).
// Block = 32-row slab x all 256 cols, 8 waves = 4 col-panels (g) x 2
// plane-pair K-halves (p). h1 stays in LDS between layers.
// ---------------------------------------------------------------------------
__global__ __launch_bounds__(512, 2) void fused2_kernel(
    const float* __restrict__ x, const float* __restrict__ ln_scale,
    const float* __restrict__ ln_bias, const float* __restrict__ alphas,
    const bf16* __restrict__ Wt, const float* __restrict__ beta,
    float* __restrict__ out) {
    extern __shared__ __align__(16) bf16 smem[];
    bf16* sxx  = smem;                 // 16896 B
    bf16* stag = smem + SXX_ELEMS;     // 131072 B: wave w owns [w*8192, +8192) elems

    const int tid = threadIdx.x;
    const int l   = tid & 63;
    const int w   = tid >> 6;
    const int g   = w >> 1, p = w & 1;
    const int slab = blockIdx.x;

    bf16* sW = stag + w * WREG;        // 16 KB: 4 buffers x 4 KB

#pragma unroll
    for (int L = 0; L < 2; ++L) {
        const float* scale = ln_scale + L * D;
        const float* biasp = ln_bias + L * D;
        const bf16*  Wl    = Wt + (size_t)L * 4 * PANEL;
        const float* bet   = beta + L * D;

        const float a  = tanhf(alphas[L]);
        const float a1 = a + 1.f;
        float rB[3], rC[3];
#pragma unroll
        for (int k = 2; k < 5; k++) {
            float tk  = 2.f * k + 2.f * a;
            float iAk = 1.f / (2.f * k * (k + 2.f * a) * (tk - 2.f));
            rB[k - 2] = (tk - 1.f) * tk * (tk - 2.f) * iAk;
            rC[k - 2] = 2.f * (k + a - 1.f) * (k + a - 1.f) * tk * iAk;
        }

        float4 sc4 = ((const float4*)scale)[l];
        float4 bi4 = ((const float4*)biasp)[l];
        float scv[4] = {sc4.x, sc4.y, sc4.z, sc4.w};
        float biv[4] = {bi4.x, bi4.y, bi4.z, bi4.w};

        // --- LN + tanh -> sxx: wave w owns rows 4w..4w+3, lane i=4l..4l+3 ---
#pragma unroll
        for (int rr = 0; rr < 4; ++rr) {
            int lr = w * 4 + rr;
            float4 v;
            if (L == 0) {
                v = ((const float4*)(x + ((size_t)slab * 32 + lr) * D))[l];
            } else {
                // h1 panel (l>>4) lives in even-wave region 2*(l>>4)
                const float* hp = (const float*)(stag + (size_t)(l >> 4) * 2 * WREG);
                v = *(const float4*)(hp + lr * 64 + (l & 15) * 4);
            }
            float s  = v.x + v.y + v.z + v.w;
            float ss = v.x * v.x + v.y * v.y + v.z * v.z + v.w * v.w;
#pragma unroll
            for (int off = 32; off > 0; off >>= 1) {
                s  += __shfl_down(s, off);
                ss += __shfl_down(ss, off);
            }
            s  = __shfl(s, 0);
            ss = __shfl(ss, 0);
            float mu   = s * (1.f / D);
            float rstd = rsqrtf(ss * (1.f / D) - mu * mu + 1e-6f);
            float hv[4] = {v.x, v.y, v.z, v.w};
            bf16x4 o;
#pragma unroll
            for (int e = 0; e < 4; ++e)
                o[e] = (bf16)fast_tanh((hv[e] - mu) * rstd * scv[e] + biv[e]);
            *(bf16x4*)(sxx + lr * SXX_STRIDE + 4 * l) = o;
        }
        __syncthreads();   // sxx ready; h1 (L=1) fully consumed -> staging reusable

        // --- prologue W prefetch: 3 sets (AFTER barrier: no WAR on h1 panels) ---
        const bf16* Wp = Wl + (size_t)g * PANEL;
#pragma unroll
        for (int s = 0; s < 3; ++s) {
            bf16* dst = sW + (s & 3) * 2048;
            const int chunk = (p * 2 + (s & 1)) * 8 + (s >> 1);
#pragma unroll
            for (int t = 0; t < 4; ++t)
                glds16(Wp + chunk * 2048 + t * 512 + l * 8, dst + t * 512);
        }

        f32x4 acc[2][4] = {};
        if (p == 0) gemm_half<0>(acc, Wp, sxx, sW, l, a1, rB[0], rB[1], rB[2], rC[0], rC[1], rC[2]);
        else        gemm_half<1>(acc, Wp, sxx, sW, l, a1, rB[0], rB[1], rB[2], rC[0], rC[1], rC[2]);

        // --- split-K reduce: p=1 dumps into OWN (idle) staging region ---
        if (p == 1) {
            f32x4* dumpr = (f32x4*)(stag + (size_t)w * WREG);
#pragma unroll
            for (int tm = 0; tm < 2; ++tm)
#pragma unroll
                for (int tn = 0; tn < 4; ++tn)
                    dumpr[(tm * 4 + tn) * 64 + l] = acc[tm][tn];
        }
        __syncthreads();

        if (p == 0) {
            f32x4* part = (f32x4*)(stag + (size_t)(w + 1) * WREG);
            if (L == 0) {
                float* hp = (float*)(stag + (size_t)w * WREG);   // h1 panel g, 32x64 fp32
#pragma unroll
                for (int tm = 0; tm < 2; ++tm)
#pragma unroll
                    for (int tn = 0; tn < 4; ++tn) {
                        int lc = 16 * tn + (l & 15);
                        float bv = bet[g * 64 + lc] * (1.f / 256.f);
                        f32x4 v = acc[tm][tn] + part[(tm * 4 + tn) * 64 + l];
                        int lr0 = 16 * tm + (l >> 4) * 4;        // C/D: row=(l>>4)*4+r
#pragma unroll
                        for (int r = 0; r < 4; ++r)
                            hp[(lr0 + r) * 64 + lc] = v[r] * (1.f / 256.f) + bv;
                    }
            } else {
#pragma unroll
                for (int tm = 0; tm < 2; ++tm)
#pragma unroll
                    for (int tn = 0; tn < 4; ++tn) {
                        int gc = g * 64 + 16 * tn + (l & 15);
                        float bv = bet[gc] * (1.f / 256.f);
                        f32x4 v = acc[tm][tn] + part[(tm * 4 + tn) * 64 + l];
                        int gr = slab * 32 + 16 * tm + (l >> 4) * 4;
#pragma unroll
                        for (int r = 0; r < 4; ++r)
                            out[(size_t)(gr + r) * D + gc] = v[r] * (1.f / 256.f) + bv;
                    }
            }
        }
        __syncthreads();   // h1 visible before next layer's LN
    }
}

// ---------------------------------------------------------------------------
extern "C" void kernel_launch(void* const* d_in, const int* in_sizes, int n_in,
                              void* d_out, int out_size, void* d_ws, size_t ws_size,
                              hipStream_t stream) {
    const float* x        = (const float*)d_in[0];
    const float* coefs    = (const float*)d_in[1];
    const float* alphas   = (const float*)d_in[2];
    const float* ln_scale = (const float*)d_in[3];
    const float* ln_bias  = (const float*)d_in[4];
    float* out = (float*)d_out;

    char* ws = (char*)d_ws;
    bf16*  Wt   = (bf16*)ws;               // 1,048,576 B
    float* beta = (float*)(ws + 1048576);  // 2,048 B

    hipFuncSetAttribute((const void*)fused2_kernel,
                        hipFuncAttributeMaxDynamicSharedMemorySize, SMEM_BYTES);

    pack_kernel<<<136, 256, 0, stream>>>(coefs, Wt, beta);
    fused2_kernel<<<256, 512, SMEM_BYTES, stream>>>(x, ln_scale, ln_bias, alphas,
                                                    Wt, beta, out);
}

// Round 12
// 93.582 us; speedup vs baseline: 1.0771x; 1.0186x over previous
//
#include <hip/hip_runtime.h>

#define D 256
#define NB 8192
#define NKC 128            // 8-elem k-chunks per 64-o panel (K=1024 packed)
#define PANEL (NKC * 512)  // 65536 bf16 elems per panel

#define SXX_STRIDE 264     // 256 + 8 pad -> staggered banks
#define SXX_ELEMS (32 * SXX_STRIDE)               // 8448 elems = 16896 B
#define WREG 4096          // dump/h1 region per wave, elems (8 KB)
#define SMEM_BYTES (SXX_ELEMS * 2 + 8 * WREG * 2) // 16896 + 65536 = 82432 B

typedef __bf16 bf16;
typedef bf16 bf16x8 __attribute__((ext_vector_type(8)));
typedef bf16 bf16x4 __attribute__((ext_vector_type(4)));
typedef float f32x4 __attribute__((ext_vector_type(4)));

__device__ __forceinline__ float fast_tanh(float x) {
    float e = __expf(2.f * x);
    return 1.f - 2.f / (e + 1.f);
}

// ---------------------------------------------------------------------------
// pack: coefs[l][i][o][c] fp32 -> tiled W planes c in order [1,4,2,3]
// (element (o, k'=plane*256+i) at panel + (k'>>3)*512 + (o&63)*8 + (k'&7));
// blocks 128..135: beta[l][o] = sum_i coefs[l][i][o][0].  [r8-verified]
// ---------------------------------------------------------------------------
__global__ __launch_bounds__(256) void pack_kernel(const float* __restrict__ coefs,
                                                   bf16* __restrict__ Wt,
                                                   float* __restrict__ beta) {
    __shared__ float t[64 * 65];
    __shared__ float accs[4][64];
    int b = blockIdx.x;
    if (b < 128) {
        int l = b >> 6, rem = b & 63;
        int c = (rem >> 4) + 1, tl = rem & 15;
        int plane = (c == 1) ? 0 : (c == 4) ? 1 : (c == 2) ? 2 : 3;
        int i0 = (tl >> 2) * 64, o0 = (tl & 3) * 64;

        for (int j = threadIdx.x; j < 4096; j += 256) {
            int i = j >> 6, o = j & 63;
            t[i * 65 + o] = coefs[(((size_t)(l * 256 + i0 + i)) * 256 + (o0 + o)) * 5 + c];
        }
        __syncthreads();
        bf16* dst = Wt + (size_t)l * (4 * PANEL)
                       + ((size_t)(tl & 3) * NKC + (plane * 256 + i0) / 8) * 512;
        for (int j = threadIdx.x; j < 4096; j += 256) {
            int il = j & 7, o = (j >> 3) & 63, ih = j >> 9;
            dst[j] = (bf16)t[(ih * 8 + il) * 65 + o];
        }
    } else {
        int lidx = b - 128;
        int l = lidx >> 2, o0 = (lidx & 3) * 64;
        int o = threadIdx.x & 63, ig = threadIdx.x >> 6;
        float sum = 0.f;
        for (int m = 0; m < 64; ++m) {
            int i = ig * 64 + m;
            sum += coefs[(((size_t)(l * 256 + i)) * 256 + (o0 + o)) * 5 + 0];
        }
        accs[ig][o] = sum;
        __syncthreads();
        if (threadIdx.x < 64)
            beta[l * 256 + o0 + threadIdx.x] = accs[0][threadIdx.x] + accs[1][threadIdx.x]
                                             + accs[2][threadIdx.x] + accs[3][threadIdx.x];
    }
}

// chunk offset (elems) of BK=32 iteration-block `it` for plane-pair half PH
#define CHOFF(PH, it) (((((PH) * 2 + ((it) & 1)) * 8) + ((it) >> 1)) * 2048)

// ---------------------------------------------------------------------------
// K-loop half: W streamed DIRECTLY L2 -> VGPR ring (no LDS for W at all —
// W has zero intra-block reuse; the tiled layout makes each fragment load a
// 64-lane x 16B coalesced read). 4-slot ring, prefetch distance 2, compiler
// inserts precise vmcnt. A-frags: r9 plane-pairing — even iters run one
// P1->P4 chain from sxx, odd iters reuse cached fragment.
// ---------------------------------------------------------------------------
template <int PH>
__device__ __forceinline__ void gemm_half(f32x4 (&acc)[2][4], bf16x8 (&wf)[4][4],
                                          const bf16* __restrict__ lane,
                                          const bf16* sxx, int l, float a1,
                                          float rB0, float rB1, float rB2,
                                          float rC0, float rC1, float rC2) {
    bf16x8 afn[2];
#pragma unroll
    for (int it = 0; it < 16; ++it) {
        // prefetch it+2 into ring slot (it+2)&3  (slots it&3, (it+1)&3 in use)
        if (it < 14) {
            const int s = (it + 2) & 3;
#pragma unroll
            for (int tn = 0; tn < 4; ++tn)
                wf[s][tn] = *(const bf16x8*)(lane + CHOFF(PH, it + 2) + tn * 128);
        }

        bf16x8 af[2];
        if ((it & 1) == 0) {
            const int j  = it >> 1;
            const int i0 = j * 32 + (l >> 4) * 8;
#pragma unroll
            for (int tm = 0; tm < 2; ++tm) {
                bf16x8 xv = *(const bf16x8*)(sxx + (16 * tm + (l & 15)) * SXX_STRIDE + i0);
#pragma unroll
                for (int jj = 0; jj < 8; ++jj) {
                    float x  = (float)xv[jj];
                    float P1 = a1 * x;
                    float P2 = rB0 * x * P1 - rC0;
                    float P3 = rB1 * x * P2 - rC1 * P1;
                    float PA, PB;
                    if (PH == 0) { PA = P1; PB = rB2 * x * P3 - rC2 * P2; }  // c=1,4
                    else         { PA = P2; PB = P3; }                        // c=2,3
                    af[tm][jj]  = (bf16)PA;
                    afn[tm][jj] = (bf16)PB;
                }
            }
        } else {
            af[0] = afn[0];
            af[1] = afn[1];
        }

        const int cur = it & 3;
#pragma unroll
        for (int tm = 0; tm < 2; ++tm)
#pragma unroll
            for (int tn = 0; tn < 4; ++tn)
                acc[tm][tn] = __builtin_amdgcn_mfma_f32_16x16x32_bf16(
                    af[tm], wf[cur][tn], acc[tm][tn], 0, 0, 0);
    }
}

// ---------------------------------------------------------------------------
// Fused 2-layer kernel. Block = 32-row slab x all 256 cols, 8 waves =
// 4 col-panels (g) x 2 plane-pair K-halves (p). h1 stays in LDS between
// layers (r9-verified epilogue/dump scheme). W prologue loads issued BEFORE
// the LN phase to hide L2 latency behind LN compute.
// ---------------------------------------------------------------------------
__global__ __launch_bounds__(512, 2) void fused2_kernel(
    const float* __restrict__ x, const float* __restrict__ ln_scale,
    const float* __restrict__ ln_bias, const float* __restrict__ alphas,
    const bf16* __restrict__ Wt, const float* __restrict__ beta,
    float* __restrict__ out) {
    extern __shared__ __align__(16) bf16 smem[];
    bf16* sxx  = smem;                 // 16896 B
    bf16* stag = smem + SXX_ELEMS;     // 65536 B: wave w owns [w*4096, +4096) elems

    const int tid = threadIdx.x;
    const int l   = tid & 63;
    const int w   = tid >> 6;
    const int g   = w >> 1, p = w & 1;
    const int slab = blockIdx.x;

#pragma unroll
    for (int L = 0; L < 2; ++L) {
        const float* scale = ln_scale + L * D;
        const float* biasp = ln_bias + L * D;
        const bf16*  Wl    = Wt + (size_t)L * 4 * PANEL;
        const float* bet   = beta + L * D;

        // lane-fixed W pointer: frag(tn, it) = lane + CHOFF(p, it) + tn*128
        const bf16* lane = Wl + (size_t)g * PANEL + (l >> 4) * 512 + (l & 15) * 8;

        // --- prologue W prefetch (registers; overlaps LN below) ---
        bf16x8 wf[4][4];
#pragma unroll
        for (int s = 0; s < 2; ++s)
#pragma unroll
            for (int tn = 0; tn < 4; ++tn)
                wf[s][tn] = *(const bf16x8*)(lane + (p * 16 + s * 8) * 2048 + tn * 128);

        const float a  = tanhf(alphas[L]);
        const float a1 = a + 1.f;
        float rB[3], rC[3];
#pragma unroll
        for (int k = 2; k < 5; k++) {
            float tk  = 2.f * k + 2.f * a;
            float iAk = 1.f / (2.f * k * (k + 2.f * a) * (tk - 2.f));
            rB[k - 2] = (tk - 1.f) * tk * (tk - 2.f) * iAk;
            rC[k - 2] = 2.f * (k + a - 1.f) * (k + a - 1.f) * tk * iAk;
        }

        float4 sc4 = ((const float4*)scale)[l];
        float4 bi4 = ((const float4*)biasp)[l];
        float scv[4] = {sc4.x, sc4.y, sc4.z, sc4.w};
        float biv[4] = {bi4.x, bi4.y, bi4.z, bi4.w};

        // --- LN + tanh -> sxx: wave w owns rows 4w..4w+3, lane i=4l..4l+3 ---
#pragma unroll
        for (int rr = 0; rr < 4; ++rr) {
            int lr = w * 4 + rr;
            float4 v;
            if (L == 0) {
                v = ((const float4*)(x + ((size_t)slab * 32 + lr) * D))[l];
            } else {
                // h1 panel (l>>4) lives in even-wave region 2*(l>>4)
                const float* hp = (const float*)(stag + (size_t)(l >> 4) * 2 * WREG);
                v = *(const float4*)(hp + lr * 64 + (l & 15) * 4);
            }
            float s  = v.x + v.y + v.z + v.w;
            float ss = v.x * v.x + v.y * v.y + v.z * v.z + v.w * v.w;
#pragma unroll
            for (int off = 32; off > 0; off >>= 1) {
                s  += __shfl_down(s, off);
                ss += __shfl_down(ss, off);
            }
            s  = __shfl(s, 0);
            ss = __shfl(ss, 0);
            float mu   = s * (1.f / D);
            float rstd = rsqrtf(ss * (1.f / D) - mu * mu + 1e-6f);
            float hv[4] = {v.x, v.y, v.z, v.w};
            bf16x4 o;
#pragma unroll
            for (int e = 0; e < 4; ++e)
                o[e] = (bf16)fast_tanh((hv[e] - mu) * rstd * scv[e] + biv[e]);
            *(bf16x4*)(sxx + lr * SXX_STRIDE + 4 * l) = o;
        }
        __syncthreads();   // sxx ready; h1 (L=1) fully consumed -> stag reusable

        f32x4 acc[2][4] = {};
        if (p == 0) gemm_half<0>(acc, wf, lane, sxx, l, a1, rB[0], rB[1], rB[2], rC[0], rC[1], rC[2]);
        else        gemm_half<1>(acc, wf, lane, sxx, l, a1, rB[0], rB[1], rB[2], rC[0], rC[1], rC[2]);

        // --- split-K reduce: p=1 dumps into OWN stag region ---
        if (p == 1) {
            f32x4* dumpr = (f32x4*)(stag + (size_t)w * WREG);
#pragma unroll
            for (int tm = 0; tm < 2; ++tm)
#pragma unroll
                for (int tn = 0; tn < 4; ++tn)
                    dumpr[(tm * 4 + tn) * 64 + l] = acc[tm][tn];
        }
        __syncthreads();

        if (p == 0) {
            f32x4* part = (f32x4*)(stag + (size_t)(w + 1) * WREG);
            if (L == 0) {
                float* hp = (float*)(stag + (size_t)w * WREG);   // h1 panel g, 32x64 fp32
#pragma unroll
                for (int tm = 0; tm < 2; ++tm)
#pragma unroll
                    for (int tn = 0; tn < 4; ++tn) {
                        int lc = 16 * tn + (l & 15);
                        float bv = bet[g * 64 + lc] * (1.f / 256.f);
                        f32x4 v = acc[tm][tn] + part[(tm * 4 + tn) * 64 + l];
                        int lr0 = 16 * tm + (l >> 4) * 4;        // C/D: row=(l>>4)*4+r
#pragma unroll
                        for (int r = 0; r < 4; ++r)
                            hp[(lr0 + r) * 64 + lc] = v[r] * (1.f / 256.f) + bv;
                    }
            } else {
#pragma unroll
                for (int tm = 0; tm < 2; ++tm)
#pragma unroll
                    for (int tn = 0; tn < 4; ++tn) {
                        int gc = g * 64 + 16 * tn + (l & 15);
                        float bv = bet[gc] * (1.f / 256.f);
                        f32x4 v = acc[tm][tn] + part[(tm * 4 + tn) * 64 + l];
                        int gr = slab * 32 + 16 * tm + (l >> 4) * 4;
#pragma unroll
                        for (int r = 0; r < 4; ++r)
                            out[(size_t)(gr + r) * D + gc] = v[r] * (1.f / 256.f) + bv;
                    }
            }
        }
        __syncthreads();   // h1 visible before next layer's LN
    }
}

// ---------------------------------------------------------------------------
extern "C" void kernel_launch(void* const* d_in, const int* in_sizes, int n_in,
                              void* d_out, int out_size, void* d_ws, size_t ws_size,
                              hipStream_t stream) {
    const float* x        = (const float*)d_in[0];
    const float* coefs    = (const float*)d_in[1];
    const float* alphas   = (const float*)d_in[2];
    const float* ln_scale = (const float*)d_in[3];
    const float* ln_bias  = (const float*)d_in[4];
    float* out = (float*)d_out;

    char* ws = (char*)d_ws;
    bf16*  Wt   = (bf16*)ws;               // 1,048,576 B
    float* beta = (float*)(ws + 1048576);  // 2,048 B

    hipFuncSetAttribute((const void*)fused2_kernel,
                        hipFuncAttributeMaxDynamicSharedMemorySize, SMEM_BYTES);

    pack_kernel<<<136, 256, 0, stream>>>(coefs, Wt, beta);
    fused2_kernel<<<256, 512, SMEM_BYTES, stream>>>(x, ln_scale, ln_bias, alphas,
                                                    Wt, beta, out);
}